// Round 13
// baseline (418.905 us; speedup 1.0000x reference)
//
#include <hip/hip_runtime.h>
#include <hip/hip_bf16.h>

typedef _Float16 f16x8 __attribute__((ext_vector_type(8)));
typedef _Float16 f16x4 __attribute__((ext_vector_type(4)));
typedef float    f32x4 __attribute__((ext_vector_type(4)));

#define EPS_ 1e-5f

__device__ __forceinline__ void gload_lds16(const _Float16* g, _Float16* l) {
    __builtin_amdgcn_global_load_lds(
        (const __attribute__((address_space(1))) void*)g,
        (__attribute__((address_space(3))) void*)l, 16, 0, 0);
}

// ---------------- elementwise / prep kernels ----------------

__global__ void k_cvt_f16(const float* __restrict__ in, _Float16* __restrict__ out, int n4) {
    int i = blockIdx.x * blockDim.x + threadIdx.x;
    int stride = gridDim.x * blockDim.x;
    const float4* in4 = (const float4*)in;
    for (; i < n4; i += stride) {
        float4 v = in4[i];
        f16x4 o;
        o[0] = (_Float16)v.x; o[1] = (_Float16)v.y;
        o[2] = (_Float16)v.z; o[3] = (_Float16)v.w;
        *(f16x4*)(out + (size_t)i * 4) = o;
    }
}

// three W [1024][1024] fp32 -> Wt [1024][1024] f16 (transposed), one launch
__global__ void k_transpose_w3(const float* __restrict__ Wa, const float* __restrict__ Wb,
                               const float* __restrict__ Wc, _Float16* __restrict__ oa,
                               _Float16* __restrict__ ob, _Float16* __restrict__ oc) {
    const float* in = blockIdx.z == 0 ? Wa : (blockIdx.z == 1 ? Wb : Wc);
    _Float16* out   = blockIdx.z == 0 ? oa : (blockIdx.z == 1 ? ob : oc);
    __shared__ float tile[32][33];
    int bx = blockIdx.x * 32;
    int by = blockIdx.y * 32;
    int tx = threadIdx.x, ty = threadIdx.y;
    #pragma unroll
    for (int r = 0; r < 32; r += 8)
        tile[ty + r][tx] = in[(size_t)(by + ty + r) * 1024 + bx + tx];
    __syncthreads();
    #pragma unroll
    for (int r = 0; r < 32; r += 8)
        out[(size_t)(bx + ty + r) * 1024 + by + tx] = (_Float16)tile[tx][ty + r];
}

// b23[o] = sum_h b2[h] * W3[h][o]
__global__ void k_b23(const float* __restrict__ b2, const float* __restrict__ W3,
                      float* __restrict__ b23) {
    const int oo = threadIdx.x & 63, hc = threadIdx.x >> 6;
    const int o = blockIdx.x * 64 + oo;
    float s = 0.f;
    for (int h = hc * 256; h < hc * 256 + 256; ++h) s += b2[h] * W3[(size_t)h * 1024 + o];
    __shared__ float red[4][64];
    red[hc][oo] = s;
    __syncthreads();
    if (threadIdx.x < 64) {
        int o2 = blockIdx.x * 64 + threadIdx.x;
        b23[o2] = red[0][threadIdx.x] + red[1][threadIdx.x] + red[2][threadIdx.x] + red[3][threadIdx.x];
    }
}

// ---------------- BN stats (from M6-epilogue partials) / normalize ----------------

// spart layout: sums at [chunk*32768 + row], sqsums at [131072 + chunk*32768 + row]
__global__ void k_bnstats2(const float* __restrict__ spart, const float* __restrict__ gamma,
                           const float* __restrict__ beta, float* __restrict__ scale,
                           float* __restrict__ shift) {
    const int n = blockIdx.x, tid = threadIdx.x;   // 256 thr: b = tid>>2, chunk = tid&3
    const int b = tid >> 2, c = tid & 3;
    const int row = b * 512 + n;
    float s = spart[c * 32768 + row];
    float q = spart[131072 + c * 32768 + row];
    #pragma unroll
    for (int o = 32; o > 0; o >>= 1) { s += __shfl_down(s, o); q += __shfl_down(q, o); }
    __shared__ float rs_[4], rq_[4];
    int lane = tid & 63, w = tid >> 6;
    if (lane == 0) { rs_[w] = s; rq_[w] = q; }
    __syncthreads();
    if (tid == 0) {
        float S = rs_[0] + rs_[1] + rs_[2] + rs_[3];
        float Q = rq_[0] + rq_[1] + rq_[2] + rq_[3];
        float mean = S * (1.f / 65536.f);
        float var  = Q * (1.f / 65536.f) - mean * mean;
        float r = rsqrtf(var + EPS_);
        float sc = gamma[n] * r;
        scale[n] = sc;
        shift[n] = beta[n] - mean * sc;
    }
}

// normalize + leaky, write theta f16 and row-mean mu
__global__ void k_bnorm(const _Float16* __restrict__ t, const float* __restrict__ scale,
                        const float* __restrict__ shift, _Float16* __restrict__ theta,
                        float* __restrict__ mu) {
    const int row = blockIdx.x, tid = threadIdx.x;
    const int n = row & 511;
    const float sc = scale[n], sh = shift[n];
    f16x4 v = *(const f16x4*)(t + (size_t)row * 1024 + tid * 4);
    float a0 = fmaf((float)v[0], sc, sh); a0 = a0 >= 0.f ? a0 : 0.01f * a0;
    float a1 = fmaf((float)v[1], sc, sh); a1 = a1 >= 0.f ? a1 : 0.01f * a1;
    float a2 = fmaf((float)v[2], sc, sh); a2 = a2 >= 0.f ? a2 : 0.01f * a2;
    float a3 = fmaf((float)v[3], sc, sh); a3 = a3 >= 0.f ? a3 : 0.01f * a3;
    float s = a0 + a1 + a2 + a3;
    #pragma unroll
    for (int o = 32; o > 0; o >>= 1) s += __shfl_down(s, o);
    __shared__ float red[4];
    int lane = tid & 63, w = tid >> 6;
    if (lane == 0) red[w] = s;
    __syncthreads();
    const float mean = (red[0] + red[1] + red[2] + red[3]) * (1.f / 1024.f);
    f16x4 th;
    th[0] = (_Float16)a0; th[1] = (_Float16)a1; th[2] = (_Float16)a2; th[3] = (_Float16)a3;
    *(f16x4*)(theta + (size_t)row * 1024 + tid * 4) = th;
    if (tid == 0) mu[row] = mean;
}

// rsum[b][j] = sum of 2 tile-chunks; ssum[b] = sum_j rsum[b][j]
__global__ void k_ssum(const float* __restrict__ part, float* __restrict__ rsum,
                       float* __restrict__ ssum) {
    const int b = blockIdx.x, j = threadIdx.x;   // 512 threads
    const int idx = b * 512 + j;
    float s = part[idx] + part[32768 + idx];
    rsum[idx] = s;
    #pragma unroll
    for (int o = 32; o > 0; o >>= 1) s += __shfl_down(s, o);
    __shared__ float red[8];
    if ((j & 63) == 0) red[j >> 6] = s;
    __syncthreads();
    if (j == 0) {
        float tt = 0.f;
        #pragma unroll
        for (int k = 0; k < 8; k++) tt += red[k];
        ssum[b] = tt;
    }
}

// ---------------- 128^2 GEMM for W23t prep only: W23t = W3t @ W2h^T ----------------

__global__ __launch_bounds__(256) void k_gemm5(
    const _Float16* __restrict__ A0, const _Float16* __restrict__ B0,
    _Float16* __restrict__ outp) {

    constexpr int BK = 32;
    __shared__ _Float16 Al[4096];
    __shared__ _Float16 Bl[4096];

    const int tid = threadIdx.x, lane = tid & 63, w = tid >> 6;
    const int wm = w >> 1, wn = w & 1;
    const int bm = blockIdx.x, bn = blockIdx.y;

    const int srow = tid >> 2;
    const int skofs = ((tid & 3) ^ ((tid >> 3) & 3)) * 8;
    _Float16* lA0 = &Al[(w * 64) * 8];
    _Float16* lA1 = &Al[(256 + w * 64) * 8];
    _Float16* lB0 = &Bl[(w * 64) * 8];
    _Float16* lB1 = &Bl[(256 + w * 64) * 8];

    const int lr = lane & 15, kg = lane >> 4;
    const int kswz = kg ^ ((lr >> 1) & 3);

    f32x4 acc[4][4] = {};

    const size_t aO = (size_t)bm * 128 * 1024;
    const size_t bO = (size_t)bn * 128 * 1024;
    for (int k0 = 0; k0 < 1024; k0 += BK) {
        gload_lds16(A0 + aO + (size_t)srow * 1024 + k0 + skofs, lA0);
        gload_lds16(A0 + aO + (size_t)(srow + 64) * 1024 + k0 + skofs, lA1);
        gload_lds16(B0 + bO + (size_t)srow * 1024 + k0 + skofs, lB0);
        gload_lds16(B0 + bO + (size_t)(srow + 64) * 1024 + k0 + skofs, lB1);
        __syncthreads();
        f16x8 af[4], bf[4];
        #pragma unroll
        for (int m = 0; m < 4; m++)
            af[m] = *(const f16x8*)&Al[((wm * 64 + m * 16 + lr) * 4 + kswz) * 8];
        #pragma unroll
        for (int n = 0; n < 4; n++)
            bf[n] = *(const f16x8*)&Bl[((wn * 64 + n * 16 + lr) * 4 + kswz) * 8];
        #pragma unroll
        for (int m = 0; m < 4; m++)
            #pragma unroll
            for (int n = 0; n < 4; n++)
                acc[m][n] = __builtin_amdgcn_mfma_f32_16x16x32_f16(af[m], bf[n], acc[m][n], 0, 0, 0);
        __syncthreads();
    }

    #pragma unroll
    for (int m = 0; m < 4; m++) {
        #pragma unroll
        for (int n = 0; n < 4; n++) {
            const int r0 = wm * 64 + m * 16 + kg * 4;
            const int gc = bn * 128 + wn * 64 + n * 16 + lr;
            #pragma unroll
            for (int i = 0; i < 4; i++)
                outp[(size_t)(bm * 128 + r0 + i) * 1024 + gc] = (_Float16)acc[m][n][i];
        }
    }
}

// ---------------- 256^2 8-phase GEMM (R8 schedule, no sched_barrier) ----------------
// M6: fused {t | gwt}: xb @ Wcat^T, Wcat = [W1t ; W23t]  M=32768 N=2048 K=1024
//     epilogue: bn<4 -> t(f16, +b1) + BN partial sums; bn>=4 -> gwt transposed
// M3: out(f32) = (att@gwt^T)*osc + xb@W4t^T + rsum*osc*b23 + b3 + b4  (K=512|1024)
// M7: att = exp(theta@theta^T/32768 - mu_i mu_j/32), symmetric: 3 tile-pairs
//     {(0,0),(0,1),(1,1)} x 64 batches; off-diag also writes E^T (LDS-staged)
//     and col-sum partials. rpart: 2 chunks, each (chunk,row) written once.
//
// R13 change: dropped per-phase __builtin_amdgcn_sched_barrier(0) (m141: order-
// pinning costs up to 1.7x). Race-freedom still holds: explicit lgkmcnt(0)
// drains each phase's ds_reads before the phase's trailing barrier, which is
// what releases the stage that overwrites the slot 2+ phases later. Compiler
// inserts its own lgkm waits before af/bf use, so MFMA hoisting is safe.

template <int MODE>
__global__ __launch_bounds__(512) void k_gemm8(
    const _Float16* __restrict__ A0, const _Float16* __restrict__ B0,
    const _Float16* __restrict__ A1, const _Float16* __restrict__ B1,
    const float* __restrict__ biasf, const float* __restrict__ biasg,
    const float* __restrict__ auxA, const float* __restrict__ auxB,
    const float* __restrict__ sumptr, void* __restrict__ outp) {

    __shared__ _Float16 LA[32768];   // 4 half-slots x [128 lines][64 k]
    __shared__ _Float16 LB[32768];

    const int tid = threadIdx.x, lane = tid & 63, wid = tid >> 6;
    const int wm = wid >> 2, wn = wid & 3;
    const int lr = lane & 15, kq = lane >> 4;

    int bm = 0, bn = 0, bz = 0, tm = 0, tn = 0;
    if constexpr (MODE == 6) {
        const int swz = (blockIdx.x & 7) * 128 + (blockIdx.x >> 3);
        bm = swz >> 3; bn = swz & 7;
    } else if constexpr (MODE == 7) {
        const int swz = (blockIdx.x & 7) * 24 + (blockIdx.x >> 3);   // 192 blocks
        bz = swz / 3;
        const int pair = swz - bz * 3;
        tm = pair >> 1; tn = (pair + 1) >> 1;   // 0->(0,0) 1->(0,1) 2->(1,1)
    } else {
        const int swz = (blockIdx.x & 7) * 64 + (blockIdx.x >> 3);
        if constexpr (MODE == 3) { bz = swz >> 3; bm = (swz >> 2) & 1; bn = swz & 3; }
        else { bm = swz >> 2; bn = swz & 3; }
    }

    constexpr int NITER = (MODE == 3) ? 12 : 8;
    float oscale = 1.f;
    if constexpr (MODE == 3) oscale = 1.f / sumptr[bz];

    size_t aBase = 0, bBase = 0;
    if constexpr (MODE == 6) {
        aBase = (size_t)bm * 256 * 1024; bBase = (size_t)bn * 256 * 1024;
    } else if constexpr (MODE == 7) {
        aBase = ((size_t)bz * 512 + tm * 256) * 1024;
        bBase = ((size_t)bz * 512 + tn * 256) * 1024;
    }

    const int i0 = tid >> 3;                    // slot line (low 64)
    const int kgs = (tid & 7) ^ (i0 & 7);       // staged logical k-chunk

    auto STAGE = [&](int g, int isA, int h) {
        const _Float16* P; int ld; size_t off; int kk;
        if constexpr (MODE == 3) {
            if (g < 8) {
                kk = g * 64;
                if (isA) { P = A0; ld = 512;  off = (size_t)bz * 262144 + (size_t)bm * 256 * 512; }
                else     { P = B0; ld = 512;  off = (size_t)bz * 524288 + (size_t)bn * 256 * 512; }
            } else {
                kk = (g - 8) * 64;
                if (isA) { P = A1; ld = 1024; off = ((size_t)bz * 512 + bm * 256) * 1024; }
                else     { P = B1; ld = 1024; off = (size_t)bn * 256 * 1024; }
            }
        } else {
            kk = g * 64;
            ld = 1024;
            if (isA) { P = A0; off = aBase; }
            else     { P = B0; off = bBase; }
        }
        const int l0 = isA ? (h * 64 + i0)
                           : ((i0 >> 5) * 64 + h * 32 + (i0 & 31));
        const int l1 = isA ? (128 + h * 64 + i0)
                           : (((i0 >> 5) + 2) * 64 + h * 32 + (i0 & 31));
        _Float16* dst = (isA ? LA : LB) + ((g & 1) * 2 + h) * 8192 + wid * 512;
        gload_lds16(P + off + (size_t)l0 * ld + kk + kgs * 8, dst);
        gload_lds16(P + off + (size_t)l1 * ld + kk + kgs * 8, dst + 4096);
    };

    f32x4 acc[8][4] = {};

    // prologue: k-tile0 (A h0, B h0, B h1, A h1) then B(1,0), B(1,1), A(1,0)
    STAGE(0, 1, 0); STAGE(0, 0, 0); STAGE(0, 0, 1); STAGE(0, 1, 1);
    STAGE(1, 0, 0); STAGE(1, 0, 1); STAGE(1, 1, 0);
    asm volatile("s_waitcnt vmcnt(6)" ::: "memory");
    __builtin_amdgcn_s_barrier();

    for (int i = 0; i < NITER; ++i) {
        if constexpr (MODE == 3) {
            if (i == 4) {   // segment A (K=512, iters 0-3) complete -> rescale
                #pragma unroll
                for (int m = 0; m < 8; m++)
                    #pragma unroll
                    for (int n = 0; n < 4; n++)
                        #pragma unroll
                        for (int v = 0; v < 4; v++) acc[m][n][v] *= oscale;
            }
        }
        const bool more = (i + 1 < NITER);
        #pragma unroll
        for (int kt = 0; kt < 2; ++kt) {
            f16x8 bf[4][2];           // all B fragments of this k-tile, live 4 phases
            #pragma unroll
            for (int sub = 0; sub < 4; ++sub) {
                const int ph = kt * 4 + sub;
                // --- ds reads ---
                if (sub == 0) {
                    #pragma unroll
                    for (int n = 0; n < 4; n++) {
                        const _Float16* Bs = LB + (kt * 2 + (n >> 1)) * 8192;
                        #pragma unroll
                        for (int s = 0; s < 2; s++)
                            bf[n][s] = *(const f16x8*)&Bs[(wn * 32 + (n & 1) * 16 + lr) * 64
                                                           + ((((s << 2) | kq) ^ (lr & 7)) << 3)];
                    }
                }
                const _Float16* As = LA + (kt * 2 + (sub >> 1)) * 8192;
                f16x8 af[2][2];
                #pragma unroll
                for (int j = 0; j < 2; j++) {
                    const int m = sub * 2 + j;
                    #pragma unroll
                    for (int s = 0; s < 2; s++)
                        af[j][s] = *(const f16x8*)&As[(wm * 64 + (m & 3) * 16 + lr) * 64
                                                       + ((((s << 2) | kq) ^ (lr & 7)) << 3)];
                }
                // --- stage issue ---
                {
                    constexpr int gof[8] = {1, 2, 2, 2, 2, 3, 3, 3};
                    constexpr int isa[8] = {1, 0, 0, 1, 1, 0, 0, 1};
                    constexpr int hh [8] = {1, 0, 1, 0, 1, 0, 1, 0};
                    if (ph == 0 || more) STAGE(2 * i + gof[ph], isa[ph], hh[ph]);
                }
                __builtin_amdgcn_s_barrier();
                asm volatile("s_waitcnt lgkmcnt(0)" ::: "memory");
                __builtin_amdgcn_s_setprio(1);
                #pragma unroll
                for (int j = 0; j < 2; j++)
                    #pragma unroll
                    for (int n = 0; n < 4; n++)
                        #pragma unroll
                        for (int s = 0; s < 2; s++)
                            acc[sub * 2 + j][n] = __builtin_amdgcn_mfma_f32_16x16x32_f16(
                                af[j][s], bf[n][s], acc[sub * 2 + j][n], 0, 0, 0);
                __builtin_amdgcn_s_setprio(0);
                if (ph == 1) { if (more) asm volatile("s_waitcnt vmcnt(10)" ::: "memory");
                               else      asm volatile("s_waitcnt vmcnt(8)"  ::: "memory"); }
                if (ph == 3) { if (more) asm volatile("s_waitcnt vmcnt(8)"  ::: "memory");
                               else      asm volatile("s_waitcnt vmcnt(2)"  ::: "memory"); }
                if (ph == 5) { if (more) asm volatile("s_waitcnt vmcnt(10)" ::: "memory");
                               else      asm volatile("s_waitcnt vmcnt(0)"  ::: "memory"); }
                if (ph == 7) { if (more) asm volatile("s_waitcnt vmcnt(8)"  ::: "memory"); }
                __builtin_amdgcn_s_barrier();
            }
        }
    }

    // ---------------- epilogues ----------------
    if constexpr (MODE == 6) {
        if (bn < 4) {   // t-side: write t and BN partial sums (block-uniform branch)
            _Float16* o = (_Float16*)outp;
            float* sbuf = (float*)LA;   // [4 wn][256 rows]
            float* qbuf = (float*)LB;
            __syncthreads();            // loop LDS use complete before reuse
            #pragma unroll
            for (int m = 0; m < 8; m++) {
                float s4[4] = {0.f, 0.f, 0.f, 0.f}, q4[4] = {0.f, 0.f, 0.f, 0.f};
                const int gr0 = bm * 256 + wm * 128 + m * 16 + kq * 4;
                #pragma unroll
                for (int n = 0; n < 4; n++) {
                    const int gc = bn * 256 + wn * 64 + n * 16 + lr;
                    const float bias = biasf[gc];
                    #pragma unroll
                    for (int i = 0; i < 4; i++) {
                        const float e = acc[m][n][i] + bias;
                        o[(size_t)(gr0 + i) * 1024 + gc] = (_Float16)e;
                        s4[i] += e; q4[i] += e * e;
                    }
                }
                #pragma unroll
                for (int i = 0; i < 4; i++) {
                    float s = s4[i], q = q4[i];
                    s += __shfl_xor(s, 1); q += __shfl_xor(q, 1);
                    s += __shfl_xor(s, 2); q += __shfl_xor(q, 2);
                    s += __shfl_xor(s, 4); q += __shfl_xor(q, 4);
                    s += __shfl_xor(s, 8); q += __shfl_xor(q, 8);
                    if (lr == 0) {
                        const int rl = wm * 128 + m * 16 + kq * 4 + i;
                        sbuf[wn * 256 + rl] = s;
                        qbuf[wn * 256 + rl] = q;
                    }
                }
            }
            __syncthreads();
            if (tid < 256) {
                const float s = sbuf[tid] + sbuf[256 + tid] + sbuf[512 + tid] + sbuf[768 + tid];
                const float q = qbuf[tid] + qbuf[256 + tid] + qbuf[512 + tid] + qbuf[768 + tid];
                float* sp = (float*)auxB;   // spart
                const int row = bm * 256 + tid;
                sp[bn * 32768 + row] = s;
                sp[131072 + bn * 32768 + row] = q;
            }
        } else {        // gwt-side: transposed [b][o][m]
            _Float16* o = (_Float16*)B1;
            #pragma unroll
            for (int m = 0; m < 8; m++) {
                #pragma unroll
                for (int n = 0; n < 4; n++) {
                    const int gc = bn * 256 + wn * 64 + n * 16 + lr;
                    const int gr0 = bm * 256 + wm * 128 + m * 16 + kq * 4;
                    const int oc = gc - 1024;
                    const int bb = gr0 >> 9, mm = gr0 & 511;
                    f16x4 pk;
                    #pragma unroll
                    for (int i = 0; i < 4; i++) pk[i] = (_Float16)acc[m][n][i];
                    *(f16x4*)(o + ((size_t)bb * 1024 + oc) * 512 + mm) = pk;
                }
            }
        }
    } else if constexpr (MODE == 7) {
        __shared__ float rbuf7[4][256];
        __shared__ float cbuf7[2][256];
        const bool diag = (tm == tn);
        _Float16* o = (_Float16*)outp + (size_t)bz * 262144;
        float* rpart = (float*)auxB;
        float csn[4] = {0.f, 0.f, 0.f, 0.f};
        __syncthreads();            // loop LDS reads complete before T reuse
        #pragma unroll
        for (int m = 0; m < 8; m++) {
            const int rloc = wm * 128 + m * 16 + kq * 4;     // local row base
            const int sidx = wm * 32 + m * 4 + kq;           // T sub-chunk (8B units)
            float rs[4] = {0.f, 0.f, 0.f, 0.f};
            #pragma unroll
            for (int n = 0; n < 4; n++) {
                const int cl = wn * 64 + n * 16 + lr;        // local col
                const float mj = auxA[bz * 512 + tn * 256 + cl];
                f16x4 pk;
                #pragma unroll
                for (int i = 0; i < 4; i++) {
                    const float mi = auxA[bz * 512 + tm * 256 + rloc + i];
                    const float e = __expf(acc[m][n][i] * (1.f / 32768.f) - mi * mj * (1.f / 32.f));
                    o[(size_t)(tm * 256 + rloc + i) * 512 + tn * 256 + cl] = (_Float16)e;
                    pk[i] = (_Float16)e;
                    rs[i] += e;
                    csn[n] += e;
                }
                if (!diag) {   // stage E^T: row cl of E^T, sub-chunk sidx (XOR-swizzled)
                    _Float16* Trow = (cl < 128) ? &LA[cl * 256] : &LB[(cl - 128) * 256];
                    *(f16x4*)&Trow[(sidx ^ ((cl & 7) << 1)) * 4] = pk;
                }
            }
            #pragma unroll
            for (int i = 0; i < 4; i++) {
                float v = rs[i];
                v += __shfl_xor(v, 1); v += __shfl_xor(v, 2);
                v += __shfl_xor(v, 4); v += __shfl_xor(v, 8);
                if (lr == 0) rbuf7[wn][rloc + i] = v;
            }
        }
        if (!diag) {
            #pragma unroll
            for (int n = 0; n < 4; n++) {
                float v = csn[n];
                v += __shfl_xor(v, 16); v += __shfl_xor(v, 32);
                if (kq == 0) cbuf7[wm][wn * 64 + n * 16 + lr] = v;
            }
        }
        __syncthreads();
        if (tid < 256) {
            const float s = rbuf7[0][tid] + rbuf7[1][tid] + rbuf7[2][tid] + rbuf7[3][tid];
            rpart[tn * 32768 + bz * 512 + tm * 256 + tid] = s;   // row sums -> chunk tn
            if (!diag)
                rpart[tm * 32768 + bz * 512 + tn * 256 + tid] =   // col sums -> chunk tm
                    cbuf7[0][tid] + cbuf7[1][tid];
        }
        if (!diag) {   // coalesced E^T write: 256 rows x 512 B
            #pragma unroll
            for (int k = 0; k < 16; k++) {
                const int q = k * 512 + tid;
                const int c = q >> 5, j = q & 31;
                const _Float16* Trow = (c < 128) ? &LA[c * 256] : &LB[(c - 128) * 256];
                f16x8 v = *(const f16x8*)&Trow[(((2 * j) ^ ((c & 7) << 1))) * 4];
                *(f16x8*)(o + (size_t)(tn * 256 + c) * 512 + tm * 256 + j * 8) = v;
            }
        }
    } else { // MODE 3
        #pragma unroll
        for (int m = 0; m < 8; m++) {
            #pragma unroll
            for (int n = 0; n < 4; n++) {
                const int gc = bn * 256 + wn * 64 + n * 16 + lr;
                const int gr0 = bm * 256 + wm * 128 + m * 16 + kq * 4;
                float* o = (float*)outp;
                const float tail = biasf[gc] + biasg[gc];
                const float b23v = auxB[gc];
                #pragma unroll
                for (int i = 0; i < 4; i++) {
                    const int row = gr0 + i;   // 0..511
                    o[((size_t)bz * 512 + row) * 1024 + gc] =
                        acc[m][n][i] + auxA[bz * 512 + row] * oscale * b23v + tail;
                }
            }
        }
    }
}

// ---------------- launcher ----------------

extern "C" void kernel_launch(void* const* d_in, const int* in_sizes, int n_in,
                              void* d_out, int out_size, void* d_ws, size_t ws_size,
                              hipStream_t stream) {
    (void)in_sizes; (void)n_in; (void)out_size; (void)ws_size;
    const float* x     = (const float*)d_in[0];
    const float* W1    = (const float*)d_in[1];
    const float* b1    = (const float*)d_in[2];
    const float* gamma = (const float*)d_in[3];
    const float* beta  = (const float*)d_in[4];
    const float* W2    = (const float*)d_in[5];
    const float* b2    = (const float*)d_in[6];
    const float* W3    = (const float*)d_in[7];
    const float* b3    = (const float*)d_in[8];
    const float* W4    = (const float*)d_in[9];
    const float* b4    = (const float*)d_in[10];

    char* wsb = (char*)d_ws;
    const size_t MB = 1024 * 1024;
    _Float16* xb    = (_Float16*)(wsb);                   // 64 MB
    _Float16* Wcat  = (_Float16*)(wsb + 64 * MB);         // [W1t | W23t] 4 MB
    _Float16* W1t   = Wcat;
    _Float16* W23t  = Wcat + 1024 * 1024;
    _Float16* W3t   = (_Float16*)(wsb + 68 * MB);
    _Float16* W4t   = (_Float16*)(wsb + 70 * MB);
    _Float16* W2h   = (_Float16*)(wsb + 72 * MB);
    float*    b23   = (float*)(wsb + 74 * MB);            // 4 KB
    float*    scl   = (float*)(wsb + 74 * MB + 8192);
    float*    shf   = (float*)(wsb + 74 * MB + 16384);
    float*    ssum  = (float*)(wsb + 74 * MB + 24576);
    float*    mu    = (float*)(wsb + 75 * MB);            // 128 KB
    float*    rsum  = (float*)(wsb + 76 * MB);            // 128 KB
    float*    rpart = (float*)(wsb + 77 * MB);            // 256 KB (2 chunks)
    float*    spart = (float*)(wsb + 78 * MB);            // 1 MB (BN partials)
    _Float16* t     = (_Float16*)(wsb + 80 * MB);         // 64 MB
    _Float16* theta = (_Float16*)(wsb + 144 * MB);        // 64 MB
    _Float16* att   = (_Float16*)(wsb + 208 * MB);        // 32 MB
    _Float16* gwt   = (_Float16*)(wsb + 240 * MB);        // 64 MB

    // prep
    k_cvt_f16<<<2048, 256, 0, stream>>>(x, xb, 64 * 512 * 1024 / 4);
    k_cvt_f16<<<1024, 256, 0, stream>>>(W2, W2h, 1024 * 1024 / 4);
    dim3 tb(32, 8), tg3(32, 32, 3);
    k_transpose_w3<<<tg3, tb, 0, stream>>>(W1, W3, W4, W1t, W3t, W4t);
    // W23t = (W2@W3)^T  (written into Wcat second half)
    k_gemm5<<<dim3(8, 8, 1), 256, 0, stream>>>(W3t, W2h, W23t);
    k_b23<<<16, 256, 0, stream>>>(b2, W3, b23);
    // fused: t = xb@W1+b1 (+BN partials) ; gwt = (xb@W23)^T   [8-phase, N=2048]
    k_gemm8<6><<<1024, 512, 0, stream>>>(xb, Wcat, nullptr, gwt,
        b1, nullptr, nullptr, spart, nullptr, t);
    // BN stats from partials + normalize
    k_bnstats2<<<512, 256, 0, stream>>>(spart, gamma, beta, scl, shf);
    k_bnorm<<<32768, 256, 0, stream>>>(t, scl, shf, theta, mu);
    // att = exp(sigma), symmetric, on the 256^2 8-phase engine (192 blocks)
    k_gemm8<7><<<192, 512, 0, stream>>>(theta, theta, nullptr, nullptr,
        nullptr, nullptr, mu, rpart, nullptr, att);
    // rsum / ssum (2 chunks)
    k_ssum<<<64, 512, 0, stream>>>(rpart, rsum, ssum);
    // out = att@gwt*osc + xb@W4 + rsum*osc*b23 + b3 + b4  [8-phase]
    k_gemm8<3><<<512, 512, 0, stream>>>(att, gwt, xb, W4t,
        b3, b4, rsum, b23, ssum, d_out);
}

// Round 14
// 410.397 us; speedup vs baseline: 1.0207x; 1.0207x over previous
//
#include <hip/hip_runtime.h>
#include <hip/hip_bf16.h>

typedef _Float16 f16x8 __attribute__((ext_vector_type(8)));
typedef _Float16 f16x4 __attribute__((ext_vector_type(4)));
typedef float    f32x4 __attribute__((ext_vector_type(4)));

#define EPS_ 1e-5f

__device__ __forceinline__ void gload_lds16(const _Float16* g, _Float16* l) {
    __builtin_amdgcn_global_load_lds(
        (const __attribute__((address_space(1))) void*)g,
        (__attribute__((address_space(3))) void*)l, 16, 0, 0);
}

// ---------------- elementwise / prep kernels ----------------

__global__ void k_cvt_f16(const float* __restrict__ in, _Float16* __restrict__ out, int n4) {
    int i = blockIdx.x * blockDim.x + threadIdx.x;
    int stride = gridDim.x * blockDim.x;
    const float4* in4 = (const float4*)in;
    for (; i < n4; i += stride) {
        float4 v = in4[i];
        f16x4 o;
        o[0] = (_Float16)v.x; o[1] = (_Float16)v.y;
        o[2] = (_Float16)v.z; o[3] = (_Float16)v.w;
        *(f16x4*)(out + (size_t)i * 4) = o;
    }
}

// three W [1024][1024] fp32 -> Wt [1024][1024] f16 (transposed), one launch
__global__ void k_transpose_w3(const float* __restrict__ Wa, const float* __restrict__ Wb,
                               const float* __restrict__ Wc, _Float16* __restrict__ oa,
                               _Float16* __restrict__ ob, _Float16* __restrict__ oc) {
    const float* in = blockIdx.z == 0 ? Wa : (blockIdx.z == 1 ? Wb : Wc);
    _Float16* out   = blockIdx.z == 0 ? oa : (blockIdx.z == 1 ? ob : oc);
    __shared__ float tile[32][33];
    int bx = blockIdx.x * 32;
    int by = blockIdx.y * 32;
    int tx = threadIdx.x, ty = threadIdx.y;
    #pragma unroll
    for (int r = 0; r < 32; r += 8)
        tile[ty + r][tx] = in[(size_t)(by + ty + r) * 1024 + bx + tx];
    __syncthreads();
    #pragma unroll
    for (int r = 0; r < 32; r += 8)
        out[(size_t)(bx + ty + r) * 1024 + by + tx] = (_Float16)tile[tx][ty + r];
}

// b23[o] = sum_h b2[h] * W3[h][o]
__global__ void k_b23(const float* __restrict__ b2, const float* __restrict__ W3,
                      float* __restrict__ b23) {
    const int oo = threadIdx.x & 63, hc = threadIdx.x >> 6;
    const int o = blockIdx.x * 64 + oo;
    float s = 0.f;
    for (int h = hc * 256; h < hc * 256 + 256; ++h) s += b2[h] * W3[(size_t)h * 1024 + o];
    __shared__ float red[4][64];
    red[hc][oo] = s;
    __syncthreads();
    if (threadIdx.x < 64) {
        int o2 = blockIdx.x * 64 + threadIdx.x;
        b23[o2] = red[0][threadIdx.x] + red[1][threadIdx.x] + red[2][threadIdx.x] + red[3][threadIdx.x];
    }
}

// ---------------- BN stats (from M6-epilogue partials) / normalize ----------------

// spart layout: sums at [chunk*32768 + row], sqsums at [131072 + chunk*32768 + row]
__global__ void k_bnstats2(const float* __restrict__ spart, const float* __restrict__ gamma,
                           const float* __restrict__ beta, float* __restrict__ scale,
                           float* __restrict__ shift) {
    const int n = blockIdx.x, tid = threadIdx.x;   // 256 thr: b = tid>>2, chunk = tid&3
    const int b = tid >> 2, c = tid & 3;
    const int row = b * 512 + n;
    float s = spart[c * 32768 + row];
    float q = spart[131072 + c * 32768 + row];
    #pragma unroll
    for (int o = 32; o > 0; o >>= 1) { s += __shfl_down(s, o); q += __shfl_down(q, o); }
    __shared__ float rs_[4], rq_[4];
    int lane = tid & 63, w = tid >> 6;
    if (lane == 0) { rs_[w] = s; rq_[w] = q; }
    __syncthreads();
    if (tid == 0) {
        float S = rs_[0] + rs_[1] + rs_[2] + rs_[3];
        float Q = rq_[0] + rq_[1] + rq_[2] + rq_[3];
        float mean = S * (1.f / 65536.f);
        float var  = Q * (1.f / 65536.f) - mean * mean;
        float r = rsqrtf(var + EPS_);
        float sc = gamma[n] * r;
        scale[n] = sc;
        shift[n] = beta[n] - mean * sc;
    }
}

// normalize + leaky, write theta f16 and row-mean mu
__global__ void k_bnorm(const _Float16* __restrict__ t, const float* __restrict__ scale,
                        const float* __restrict__ shift, _Float16* __restrict__ theta,
                        float* __restrict__ mu) {
    const int row = blockIdx.x, tid = threadIdx.x;
    const int n = row & 511;
    const float sc = scale[n], sh = shift[n];
    f16x4 v = *(const f16x4*)(t + (size_t)row * 1024 + tid * 4);
    float a0 = fmaf((float)v[0], sc, sh); a0 = a0 >= 0.f ? a0 : 0.01f * a0;
    float a1 = fmaf((float)v[1], sc, sh); a1 = a1 >= 0.f ? a1 : 0.01f * a1;
    float a2 = fmaf((float)v[2], sc, sh); a2 = a2 >= 0.f ? a2 : 0.01f * a2;
    float a3 = fmaf((float)v[3], sc, sh); a3 = a3 >= 0.f ? a3 : 0.01f * a3;
    float s = a0 + a1 + a2 + a3;
    #pragma unroll
    for (int o = 32; o > 0; o >>= 1) s += __shfl_down(s, o);
    __shared__ float red[4];
    int lane = tid & 63, w = tid >> 6;
    if (lane == 0) red[w] = s;
    __syncthreads();
    const float mean = (red[0] + red[1] + red[2] + red[3]) * (1.f / 1024.f);
    f16x4 th;
    th[0] = (_Float16)a0; th[1] = (_Float16)a1; th[2] = (_Float16)a2; th[3] = (_Float16)a3;
    *(f16x4*)(theta + (size_t)row * 1024 + tid * 4) = th;
    if (tid == 0) mu[row] = mean;
}

// rsum[b][j] = sum of 2 tile-chunks; ssum[b] = sum_j rsum[b][j]
__global__ void k_ssum(const float* __restrict__ part, float* __restrict__ rsum,
                       float* __restrict__ ssum) {
    const int b = blockIdx.x, j = threadIdx.x;   // 512 threads
    const int idx = b * 512 + j;
    float s = part[idx] + part[32768 + idx];
    rsum[idx] = s;
    #pragma unroll
    for (int o = 32; o > 0; o >>= 1) s += __shfl_down(s, o);
    __shared__ float red[8];
    if ((j & 63) == 0) red[j >> 6] = s;
    __syncthreads();
    if (j == 0) {
        float tt = 0.f;
        #pragma unroll
        for (int k = 0; k < 8; k++) tt += red[k];
        ssum[b] = tt;
    }
}

// ---------------- 128^2 GEMM for W23t prep only: W23t = W3t @ W2h^T ----------------

__global__ __launch_bounds__(256) void k_gemm5(
    const _Float16* __restrict__ A0, const _Float16* __restrict__ B0,
    _Float16* __restrict__ outp) {

    constexpr int BK = 32;
    __shared__ _Float16 Al[4096];
    __shared__ _Float16 Bl[4096];

    const int tid = threadIdx.x, lane = tid & 63, w = tid >> 6;
    const int wm = w >> 1, wn = w & 1;
    const int bm = blockIdx.x, bn = blockIdx.y;

    const int srow = tid >> 2;
    const int skofs = ((tid & 3) ^ ((tid >> 3) & 3)) * 8;
    _Float16* lA0 = &Al[(w * 64) * 8];
    _Float16* lA1 = &Al[(256 + w * 64) * 8];
    _Float16* lB0 = &Bl[(w * 64) * 8];
    _Float16* lB1 = &Bl[(256 + w * 64) * 8];

    const int lr = lane & 15, kg = lane >> 4;
    const int kswz = kg ^ ((lr >> 1) & 3);

    f32x4 acc[4][4] = {};

    const size_t aO = (size_t)bm * 128 * 1024;
    const size_t bO = (size_t)bn * 128 * 1024;
    for (int k0 = 0; k0 < 1024; k0 += BK) {
        gload_lds16(A0 + aO + (size_t)srow * 1024 + k0 + skofs, lA0);
        gload_lds16(A0 + aO + (size_t)(srow + 64) * 1024 + k0 + skofs, lA1);
        gload_lds16(B0 + bO + (size_t)srow * 1024 + k0 + skofs, lB0);
        gload_lds16(B0 + bO + (size_t)(srow + 64) * 1024 + k0 + skofs, lB1);
        __syncthreads();
        f16x8 af[4], bf[4];
        #pragma unroll
        for (int m = 0; m < 4; m++)
            af[m] = *(const f16x8*)&Al[((wm * 64 + m * 16 + lr) * 4 + kswz) * 8];
        #pragma unroll
        for (int n = 0; n < 4; n++)
            bf[n] = *(const f16x8*)&Bl[((wn * 64 + n * 16 + lr) * 4 + kswz) * 8];
        #pragma unroll
        for (int m = 0; m < 4; m++)
            #pragma unroll
            for (int n = 0; n < 4; n++)
                acc[m][n] = __builtin_amdgcn_mfma_f32_16x16x32_f16(af[m], bf[n], acc[m][n], 0, 0, 0);
        __syncthreads();
    }

    #pragma unroll
    for (int m = 0; m < 4; m++) {
        #pragma unroll
        for (int n = 0; n < 4; n++) {
            const int r0 = wm * 64 + m * 16 + kg * 4;
            const int gc = bn * 128 + wn * 64 + n * 16 + lr;
            #pragma unroll
            for (int i = 0; i < 4; i++)
                outp[(size_t)(bm * 128 + r0 + i) * 1024 + gc] = (_Float16)acc[m][n][i];
        }
    }
}

// ---------------- 256^2 8-phase GEMM ----------------
// M6: fused {t | gwt}: xb @ Wcat^T, Wcat = [W1t ; W23t]  M=32768 N=2048 K=1024
//     epilogue: bn<4 -> t(f16, +b1) + BN partial sums;
//               bn>=4 -> gwt transposed via LDS staging (R14: no more scatter)
// M3: out(f32) = (att@gwt^T)*osc + xb@W4t^T + rsum*osc*b23 + b3 + b4  (K=512|1024)
// M7: att = exp(theta@theta^T/32768 - mu_i mu_j/32), symmetric: 3 tile-pairs
//     {(0,0),(0,1),(1,1)} x 64 batches; off-diag also writes E^T (LDS-staged)
//     and col-sum partials. rpart: 2 chunks, each (chunk,row) written once.

template <int MODE>
__global__ __launch_bounds__(512) void k_gemm8(
    const _Float16* __restrict__ A0, const _Float16* __restrict__ B0,
    const _Float16* __restrict__ A1, const _Float16* __restrict__ B1,
    const float* __restrict__ biasf, const float* __restrict__ biasg,
    const float* __restrict__ auxA, const float* __restrict__ auxB,
    const float* __restrict__ sumptr, void* __restrict__ outp) {

    __shared__ _Float16 LA[32768];   // 4 half-slots x [128 lines][64 k]
    __shared__ _Float16 LB[32768];

    const int tid = threadIdx.x, lane = tid & 63, wid = tid >> 6;
    const int wm = wid >> 2, wn = wid & 3;
    const int lr = lane & 15, kq = lane >> 4;

    int bm = 0, bn = 0, bz = 0, tm = 0, tn = 0;
    if constexpr (MODE == 6) {
        const int swz = (blockIdx.x & 7) * 128 + (blockIdx.x >> 3);
        bm = swz >> 3; bn = swz & 7;
    } else if constexpr (MODE == 7) {
        const int swz = (blockIdx.x & 7) * 24 + (blockIdx.x >> 3);   // 192 blocks
        bz = swz / 3;
        const int pair = swz - bz * 3;
        tm = pair >> 1; tn = (pair + 1) >> 1;   // 0->(0,0) 1->(0,1) 2->(1,1)
    } else {
        const int swz = (blockIdx.x & 7) * 64 + (blockIdx.x >> 3);
        if constexpr (MODE == 3) { bz = swz >> 3; bm = (swz >> 2) & 1; bn = swz & 3; }
        else { bm = swz >> 2; bn = swz & 3; }
    }

    constexpr int NITER = (MODE == 3) ? 12 : 8;
    float oscale = 1.f;
    if constexpr (MODE == 3) oscale = 1.f / sumptr[bz];

    size_t aBase = 0, bBase = 0;
    if constexpr (MODE == 6) {
        aBase = (size_t)bm * 256 * 1024; bBase = (size_t)bn * 256 * 1024;
    } else if constexpr (MODE == 7) {
        aBase = ((size_t)bz * 512 + tm * 256) * 1024;
        bBase = ((size_t)bz * 512 + tn * 256) * 1024;
    }

    const int i0 = tid >> 3;                    // slot line (low 64)
    const int kgs = (tid & 7) ^ (i0 & 7);       // staged logical k-chunk

    auto STAGE = [&](int g, int isA, int h) {
        const _Float16* P; int ld; size_t off; int kk;
        if constexpr (MODE == 3) {
            if (g < 8) {
                kk = g * 64;
                if (isA) { P = A0; ld = 512;  off = (size_t)bz * 262144 + (size_t)bm * 256 * 512; }
                else     { P = B0; ld = 512;  off = (size_t)bz * 524288 + (size_t)bn * 256 * 512; }
            } else {
                kk = (g - 8) * 64;
                if (isA) { P = A1; ld = 1024; off = ((size_t)bz * 512 + bm * 256) * 1024; }
                else     { P = B1; ld = 1024; off = (size_t)bn * 256 * 1024; }
            }
        } else {
            kk = g * 64;
            ld = 1024;
            if (isA) { P = A0; off = aBase; }
            else     { P = B0; off = bBase; }
        }
        const int l0 = isA ? (h * 64 + i0)
                           : ((i0 >> 5) * 64 + h * 32 + (i0 & 31));
        const int l1 = isA ? (128 + h * 64 + i0)
                           : (((i0 >> 5) + 2) * 64 + h * 32 + (i0 & 31));
        _Float16* dst = (isA ? LA : LB) + ((g & 1) * 2 + h) * 8192 + wid * 512;
        gload_lds16(P + off + (size_t)l0 * ld + kk + kgs * 8, dst);
        gload_lds16(P + off + (size_t)l1 * ld + kk + kgs * 8, dst + 4096);
    };

    f32x4 acc[8][4] = {};

    // prologue: k-tile0 (A h0, B h0, B h1, A h1) then B(1,0), B(1,1), A(1,0)
    STAGE(0, 1, 0); STAGE(0, 0, 0); STAGE(0, 0, 1); STAGE(0, 1, 1);
    STAGE(1, 0, 0); STAGE(1, 0, 1); STAGE(1, 1, 0);
    asm volatile("s_waitcnt vmcnt(6)" ::: "memory");
    __builtin_amdgcn_s_barrier();

    for (int i = 0; i < NITER; ++i) {
        if constexpr (MODE == 3) {
            if (i == 4) {   // segment A (K=512, iters 0-3) complete -> rescale
                #pragma unroll
                for (int m = 0; m < 8; m++)
                    #pragma unroll
                    for (int n = 0; n < 4; n++)
                        #pragma unroll
                        for (int v = 0; v < 4; v++) acc[m][n][v] *= oscale;
            }
        }
        const bool more = (i + 1 < NITER);
        #pragma unroll
        for (int kt = 0; kt < 2; ++kt) {
            f16x8 bf[4][2];           // all B fragments of this k-tile, live 4 phases
            #pragma unroll
            for (int sub = 0; sub < 4; ++sub) {
                const int ph = kt * 4 + sub;
                // --- ds reads ---
                if (sub == 0) {
                    #pragma unroll
                    for (int n = 0; n < 4; n++) {
                        const _Float16* Bs = LB + (kt * 2 + (n >> 1)) * 8192;
                        #pragma unroll
                        for (int s = 0; s < 2; s++)
                            bf[n][s] = *(const f16x8*)&Bs[(wn * 32 + (n & 1) * 16 + lr) * 64
                                                           + ((((s << 2) | kq) ^ (lr & 7)) << 3)];
                    }
                }
                const _Float16* As = LA + (kt * 2 + (sub >> 1)) * 8192;
                f16x8 af[2][2];
                #pragma unroll
                for (int j = 0; j < 2; j++) {
                    const int m = sub * 2 + j;
                    #pragma unroll
                    for (int s = 0; s < 2; s++)
                        af[j][s] = *(const f16x8*)&As[(wm * 64 + (m & 3) * 16 + lr) * 64
                                                       + ((((s << 2) | kq) ^ (lr & 7)) << 3)];
                }
                // --- stage issue ---
                {
                    constexpr int gof[8] = {1, 2, 2, 2, 2, 3, 3, 3};
                    constexpr int isa[8] = {1, 0, 0, 1, 1, 0, 0, 1};
                    constexpr int hh [8] = {1, 0, 1, 0, 1, 0, 1, 0};
                    if (ph == 0 || more) STAGE(2 * i + gof[ph], isa[ph], hh[ph]);
                }
                __builtin_amdgcn_s_barrier();
                asm volatile("s_waitcnt lgkmcnt(0)" ::: "memory");
                __builtin_amdgcn_s_setprio(1);
                #pragma unroll
                for (int j = 0; j < 2; j++)
                    #pragma unroll
                    for (int n = 0; n < 4; n++)
                        #pragma unroll
                        for (int s = 0; s < 2; s++)
                            acc[sub * 2 + j][n] = __builtin_amdgcn_mfma_f32_16x16x32_f16(
                                af[j][s], bf[n][s], acc[sub * 2 + j][n], 0, 0, 0);
                __builtin_amdgcn_s_setprio(0);
                if (ph == 1) { if (more) asm volatile("s_waitcnt vmcnt(10)" ::: "memory");
                               else      asm volatile("s_waitcnt vmcnt(8)"  ::: "memory"); }
                if (ph == 3) { if (more) asm volatile("s_waitcnt vmcnt(8)"  ::: "memory");
                               else      asm volatile("s_waitcnt vmcnt(2)"  ::: "memory"); }
                if (ph == 5) { if (more) asm volatile("s_waitcnt vmcnt(10)" ::: "memory");
                               else      asm volatile("s_waitcnt vmcnt(0)"  ::: "memory"); }
                if (ph == 7) { if (more) asm volatile("s_waitcnt vmcnt(8)"  ::: "memory"); }
                __builtin_amdgcn_s_barrier();
            }
        }
    }

    // ---------------- epilogues ----------------
    if constexpr (MODE == 6) {
        if (bn < 4) {   // t-side: write t and BN partial sums (block-uniform branch)
            _Float16* o = (_Float16*)outp;
            float* sbuf = (float*)LA;   // [4 wn][256 rows]
            float* qbuf = (float*)LB;
            __syncthreads();            // loop LDS use complete before reuse
            #pragma unroll
            for (int m = 0; m < 8; m++) {
                float s4[4] = {0.f, 0.f, 0.f, 0.f}, q4[4] = {0.f, 0.f, 0.f, 0.f};
                const int gr0 = bm * 256 + wm * 128 + m * 16 + kq * 4;
                #pragma unroll
                for (int n = 0; n < 4; n++) {
                    const int gc = bn * 256 + wn * 64 + n * 16 + lr;
                    const float bias = biasf[gc];
                    #pragma unroll
                    for (int i = 0; i < 4; i++) {
                        const float e = acc[m][n][i] + bias;
                        o[(size_t)(gr0 + i) * 1024 + gc] = (_Float16)e;
                        s4[i] += e; q4[i] += e * e;
                    }
                }
                #pragma unroll
                for (int i = 0; i < 4; i++) {
                    float s = s4[i], q = q4[i];
                    s += __shfl_xor(s, 1); q += __shfl_xor(q, 1);
                    s += __shfl_xor(s, 2); q += __shfl_xor(q, 2);
                    s += __shfl_xor(s, 4); q += __shfl_xor(q, 4);
                    s += __shfl_xor(s, 8); q += __shfl_xor(q, 8);
                    if (lr == 0) {
                        const int rl = wm * 128 + m * 16 + kq * 4 + i;
                        sbuf[wn * 256 + rl] = s;
                        qbuf[wn * 256 + rl] = q;
                    }
                }
            }
            __syncthreads();
            if (tid < 256) {
                const float s = sbuf[tid] + sbuf[256 + tid] + sbuf[512 + tid] + sbuf[768 + tid];
                const float q = qbuf[tid] + qbuf[256 + tid] + qbuf[512 + tid] + qbuf[768 + tid];
                float* sp = (float*)auxB;   // spart
                const int row = bm * 256 + tid;
                sp[bn * 32768 + row] = s;
                sp[131072 + bn * 32768 + row] = q;
            }
        } else {        // gwt-side: transposed [b][o][m], LDS-staged (M7's verified pattern)
            _Float16* o = (_Float16*)B1;
            const int bb  = bm >> 1;              // batch index (one per block)
            const int mmb = (bm & 1) * 256;       // m base within batch
            const int ocb = bn * 256 - 1024;      // o base
            __syncthreads();                      // loop LDS reads done before T reuse
            #pragma unroll
            for (int m = 0; m < 8; m++) {
                const int sidx = wm * 32 + m * 4 + kq;   // T sub-chunk (f16x4 units)
                #pragma unroll
                for (int n = 0; n < 4; n++) {
                    const int ol = wn * 64 + n * 16 + lr;   // local o
                    f16x4 pk;
                    #pragma unroll
                    for (int i = 0; i < 4; i++) pk[i] = (_Float16)acc[m][n][i];
                    _Float16* Trow = (ol < 128) ? &LA[ol * 256] : &LB[(ol - 128) * 256];
                    *(f16x4*)&Trow[(sidx ^ ((ol & 7) << 1)) * 4] = pk;
                }
            }
            __syncthreads();
            #pragma unroll
            for (int k = 0; k < 16; k++) {
                const int q = k * 512 + tid;
                const int c = q >> 5, j = q & 31;    // c = local o row, j = 16B chunk
                const _Float16* Trow = (c < 128) ? &LA[c * 256] : &LB[(c - 128) * 256];
                f16x8 v = *(const f16x8*)&Trow[(((2 * j) ^ ((c & 7) << 1))) * 4];
                *(f16x8*)(o + ((size_t)bb * 1024 + ocb + c) * 512 + mmb + j * 8) = v;
            }
        }
    } else if constexpr (MODE == 7) {
        __shared__ float rbuf7[4][256];
        __shared__ float cbuf7[2][256];
        const bool diag = (tm == tn);
        _Float16* o = (_Float16*)outp + (size_t)bz * 262144;
        float* rpart = (float*)auxB;
        float csn[4] = {0.f, 0.f, 0.f, 0.f};
        __syncthreads();            // loop LDS reads complete before T reuse
        #pragma unroll
        for (int m = 0; m < 8; m++) {
            const int rloc = wm * 128 + m * 16 + kq * 4;     // local row base
            const int sidx = wm * 32 + m * 4 + kq;           // T sub-chunk (8B units)
            float rs[4] = {0.f, 0.f, 0.f, 0.f};
            #pragma unroll
            for (int n = 0; n < 4; n++) {
                const int cl = wn * 64 + n * 16 + lr;        // local col
                const float mj = auxA[bz * 512 + tn * 256 + cl];
                f16x4 pk;
                #pragma unroll
                for (int i = 0; i < 4; i++) {
                    const float mi = auxA[bz * 512 + tm * 256 + rloc + i];
                    const float e = __expf(acc[m][n][i] * (1.f / 32768.f) - mi * mj * (1.f / 32.f));
                    o[(size_t)(tm * 256 + rloc + i) * 512 + tn * 256 + cl] = (_Float16)e;
                    pk[i] = (_Float16)e;
                    rs[i] += e;
                    csn[n] += e;
                }
                if (!diag) {   // stage E^T: row cl of E^T, sub-chunk sidx (XOR-swizzled)
                    _Float16* Trow = (cl < 128) ? &LA[cl * 256] : &LB[(cl - 128) * 256];
                    *(f16x4*)&Trow[(sidx ^ ((cl & 7) << 1)) * 4] = pk;
                }
            }
            #pragma unroll
            for (int i = 0; i < 4; i++) {
                float v = rs[i];
                v += __shfl_xor(v, 1); v += __shfl_xor(v, 2);
                v += __shfl_xor(v, 4); v += __shfl_xor(v, 8);
                if (lr == 0) rbuf7[wn][rloc + i] = v;
            }
        }
        if (!diag) {
            #pragma unroll
            for (int n = 0; n < 4; n++) {
                float v = csn[n];
                v += __shfl_xor(v, 16); v += __shfl_xor(v, 32);
                if (kq == 0) cbuf7[wm][wn * 64 + n * 16 + lr] = v;
            }
        }
        __syncthreads();
        if (tid < 256) {
            const float s = rbuf7[0][tid] + rbuf7[1][tid] + rbuf7[2][tid] + rbuf7[3][tid];
            rpart[tn * 32768 + bz * 512 + tm * 256 + tid] = s;   // row sums -> chunk tn
            if (!diag)
                rpart[tm * 32768 + bz * 512 + tn * 256 + tid] =   // col sums -> chunk tm
                    cbuf7[0][tid] + cbuf7[1][tid];
        }
        if (!diag) {   // coalesced E^T write: 256 rows x 512 B
            #pragma unroll
            for (int k = 0; k < 16; k++) {
                const int q = k * 512 + tid;
                const int c = q >> 5, j = q & 31;
                const _Float16* Trow = (c < 128) ? &LA[c * 256] : &LB[(c - 128) * 256];
                f16x8 v = *(const f16x8*)&Trow[(((2 * j) ^ ((c & 7) << 1))) * 4];
                *(f16x8*)(o + (size_t)(tn * 256 + c) * 512 + tm * 256 + j * 8) = v;
            }
        }
    } else { // MODE 3
        #pragma unroll
        for (int m = 0; m < 8; m++) {
            #pragma unroll
            for (int n = 0; n < 4; n++) {
                const int gc = bn * 256 + wn * 64 + n * 16 + lr;
                const int gr0 = bm * 256 + wm * 128 + m * 16 + kq * 4;
                float* o = (float*)outp;
                const float tail = biasf[gc] + biasg[gc];
                const float b23v = auxB[gc];
                #pragma unroll
                for (int i = 0; i < 4; i++) {
                    const int row = gr0 + i;   // 0..511
                    o[((size_t)bz * 512 + row) * 1024 + gc] =
                        acc[m][n][i] + auxA[bz * 512 + row] * oscale * b23v + tail;
                }
            }
        }
    }
}

// ---------------- launcher ----------------

extern "C" void kernel_launch(void* const* d_in, const int* in_sizes, int n_in,
                              void* d_out, int out_size, void* d_ws, size_t ws_size,
                              hipStream_t stream) {
    (void)in_sizes; (void)n_in; (void)out_size; (void)ws_size;
    const float* x     = (const float*)d_in[0];
    const float* W1    = (const float*)d_in[1];
    const float* b1    = (const float*)d_in[2];
    const float* gamma = (const float*)d_in[3];
    const float* beta  = (const float*)d_in[4];
    const float* W2    = (const float*)d_in[5];
    const float* b2    = (const float*)d_in[6];
    const float* W3    = (const float*)d_in[7];
    const float* b3    = (const float*)d_in[8];
    const float* W4    = (const float*)d_in[9];
    const float* b4    = (const float*)d_in[10];

    char* wsb = (char*)d_ws;
    const size_t MB = 1024 * 1024;
    _Float16* xb    = (_Float16*)(wsb);                   // 64 MB
    _Float16* Wcat  = (_Float16*)(wsb + 64 * MB);         // [W1t | W23t] 4 MB
    _Float16* W1t   = Wcat;
    _Float16* W23t  = Wcat + 1024 * 1024;
    _Float16* W3t   = (_Float16*)(wsb + 68 * MB);
    _Float16* W4t   = (_Float16*)(wsb + 70 * MB);
    _Float16* W2h   = (_Float16*)(wsb + 72 * MB);
    float*    b23   = (float*)(wsb + 74 * MB);            // 4 KB
    float*    scl   = (float*)(wsb + 74 * MB + 8192);
    float*    shf   = (float*)(wsb + 74 * MB + 16384);
    float*    ssum  = (float*)(wsb + 74 * MB + 24576);
    float*    mu    = (float*)(wsb + 75 * MB);            // 128 KB
    float*    rsum  = (float*)(wsb + 76 * MB);            // 128 KB
    float*    rpart = (float*)(wsb + 77 * MB);            // 256 KB (2 chunks)
    float*    spart = (float*)(wsb + 78 * MB);            // 1 MB (BN partials)
    _Float16* t     = (_Float16*)(wsb + 80 * MB);         // 64 MB
    _Float16* theta = (_Float16*)(wsb + 144 * MB);        // 64 MB
    _Float16* att   = (_Float16*)(wsb + 208 * MB);        // 32 MB
    _Float16* gwt   = (_Float16*)(wsb + 240 * MB);        // 64 MB

    // prep
    k_cvt_f16<<<2048, 256, 0, stream>>>(x, xb, 64 * 512 * 1024 / 4);
    k_cvt_f16<<<1024, 256, 0, stream>>>(W2, W2h, 1024 * 1024 / 4);
    dim3 tb(32, 8), tg3(32, 32, 3);
    k_transpose_w3<<<tg3, tb, 0, stream>>>(W1, W3, W4, W1t, W3t, W4t);
    // W23t = (W2@W3)^T  (written into Wcat second half)
    k_gemm5<<<dim3(8, 8, 1), 256, 0, stream>>>(W3t, W2h, W23t);
    k_b23<<<16, 256, 0, stream>>>(b2, W3, b23);
    // fused: t = xb@W1+b1 (+BN partials) ; gwt = (xb@W23)^T   [8-phase, N=2048]
    k_gemm8<6><<<1024, 512, 0, stream>>>(xb, Wcat, nullptr, gwt,
        b1, nullptr, nullptr, spart, nullptr, t);
    // BN stats from partials + normalize
    k_bnstats2<<<512, 256, 0, stream>>>(spart, gamma, beta, scl, shf);
    k_bnorm<<<32768, 256, 0, stream>>>(t, scl, shf, theta, mu);
    // att = exp(sigma), symmetric, on the 256^2 8-phase engine (192 blocks)
    k_gemm8<7><<<192, 512, 0, stream>>>(theta, theta, nullptr, nullptr,
        nullptr, nullptr, mu, rpart, nullptr, att);
    // rsum / ssum (2 chunks)
    k_ssum<<<64, 512, 0, stream>>>(rpart, rsum, ssum);
    // out = att@gwt*osc + xb@W4 + rsum*osc*b23 + b3 + b4  [8-phase]
    k_gemm8<3><<<512, 512, 0, stream>>>(att, gwt, xb, W4t,
        b3, b4, rsum, b23, ssum, d_out);
}